// Round 3
// baseline (13108.849 us; speedup 1.0000x reference)
//
#include <hip/hip_runtime.h>

#define THREADS 256
#define ROWS 16
#define DD 512
#define HIDN 512
#define TT 16
#define OUTN 7

// async global->LDS, 16B per lane; LDS dest = wave-uniform base + lane*16
#define GLD_LDS(g, l) __builtin_amdgcn_global_load_lds(                     \
    (const __attribute__((address_space(1))) void*)(g),                     \
    (__attribute__((address_space(3))) void*)(l), 16, 0, 0)

// ---- weight pre-pack: pack[mat][k/4][col][k%4], mat0=Wgc, mat1=Wd1_top ----
// Gives the main kernel one coalesced dwordx4 per (col, 4k) weight slice.
__global__ __launch_bounds__(256)
void pack_weights_kernel(const float* __restrict__ Wgc,
                         const float* __restrict__ Wd1,
                         float* __restrict__ pack)
{
    const int idx = blockIdx.x * 256 + threadIdx.x;   // 0 .. 2*512*512-1
    const int m   = idx >> 18;
    const int rem = idx & 262143;
    const int k   = rem >> 9;
    const int c   = rem & 511;
    const float v = (m ? Wd1 : Wgc)[(size_t)k * HIDN + c];
    pack[(size_t)m * 262144 + (size_t)(k >> 2) * 2048 + c * 4 + (k & 3)] = v;
}

// One block owns ROWS batch rows for the entire T-loop.
// Membrane state in registers; spikes as 512-bit ballot masks in LDS with a
// per-layer row-summary; dense part = xt @ [W_gc | W_d1_top] with packed
// dwordx4 weight loads; recurrent matmuls are spike-driven row accumulation.
__global__ __launch_bounds__(THREADS, 2)
void snn_fused_kernel(const float* __restrict__ x,
                      const float4* __restrict__ pack4,
                      const float* __restrict__ bgc,
                      const float* __restrict__ Wpc, const float* __restrict__ bpc,
                      const float* __restrict__ Wd1, const float* __restrict__ bd1p,
                      const float* __restrict__ Wd2, const float* __restrict__ bd2,
                      float* __restrict__ out, int B)
{
    __shared__ float xs[ROWS * DD];                 // 32 KB x-tile
    __shared__ unsigned long long bits1[ROWS][8];   // gc spikes
    __shared__ unsigned long long bits2[ROWS][8];   // pc spikes
    __shared__ unsigned long long bits3[ROWS][8];   // s3 spikes
    __shared__ unsigned int rowflag[3];             // per-layer "row has spikes"

    const int tid  = threadIdx.x;
    const int lane = tid & 63;
    const int wave = tid >> 6;
    const size_t row0 = (size_t)blockIdx.x * ROWS;

    // packed weight base pointers (float4 index = mat*65536 + k4*512 + col)
    const float4* g0 = pack4 + tid;                  // Wgc col tid
    const float4* g1 = pack4 + tid + 256;            // Wgc col tid+256
    const float4* d0 = pack4 + 65536 + tid;          // Wd1t col tid
    const float4* d1 = pack4 + 65536 + tid + 256;    // Wd1t col tid+256

    float m1a[ROWS], m1b[ROWS], m2a[ROWS], m2b[ROWS], m3a[ROWS], m3b[ROWS];
#pragma unroll
    for (int r = 0; r < ROWS; ++r) {
        m1a[r] = 0.f; m1b[r] = 0.f; m2a[r] = 0.f;
        m2b[r] = 0.f; m3a[r] = 0.f; m3b[r] = 0.f;
    }

    const float bg0 = bgc[tid],  bg1 = bgc[tid + 256];
    const float bp0 = bpc[tid],  bp1 = bpc[tid + 256];
    const float bd0 = bd1p[tid], bd1 = bd1p[tid + 256];

    float out_acc = 0.f;
    const int orow = tid / OUTN;
    const int ocol = tid - orow * OUTN;
    const bool owrite = (tid < ROWS * OUTN);

    // ---- pre-loop: zero flags, async-stage xs for t=0
    if (tid < 3) rowflag[tid] = 0;
    {
        const float* src = x + row0 * DD;
#pragma unroll
        for (int u = 0; u < 8; ++u)
            GLD_LDS(src + ((u * THREADS + tid) << 2), xs + ((u * THREADS + wave * 64) << 2));
    }
    __syncthreads();

    for (int t = 0; t < TT; ++t) {
        // ================= dense GEMM over xs (ping-pong weight prefetch) ======
        float a0[ROWS], a1[ROWS], a2[ROWS], a3[ROWS];
#pragma unroll
        for (int r = 0; r < ROWS; ++r) { a0[r] = 0.f; a1[r] = 0.f; a2[r] = 0.f; a3[r] = 0.f; }

        float4 A0 = g0[0], A1 = g1[0], A2 = d0[0], A3 = d1[0];
#pragma unroll 1
        for (int k4 = 0; k4 < 128; k4 += 2) {
            const int kk = k4 << 2;
            float4 B0 = g0[(size_t)(k4 + 1) * 512];
            float4 B1 = g1[(size_t)(k4 + 1) * 512];
            float4 B2 = d0[(size_t)(k4 + 1) * 512];
            float4 B3 = d1[(size_t)(k4 + 1) * 512];
#pragma unroll
            for (int r = 0; r < ROWS; ++r) {
                const float4 xv = *reinterpret_cast<const float4*>(&xs[r * DD + kk]);
                a0[r] = fmaf(xv.x, A0.x, a0[r]); a0[r] = fmaf(xv.y, A0.y, a0[r]);
                a0[r] = fmaf(xv.z, A0.z, a0[r]); a0[r] = fmaf(xv.w, A0.w, a0[r]);
                a1[r] = fmaf(xv.x, A1.x, a1[r]); a1[r] = fmaf(xv.y, A1.y, a1[r]);
                a1[r] = fmaf(xv.z, A1.z, a1[r]); a1[r] = fmaf(xv.w, A1.w, a1[r]);
                a2[r] = fmaf(xv.x, A2.x, a2[r]); a2[r] = fmaf(xv.y, A2.y, a2[r]);
                a2[r] = fmaf(xv.z, A2.z, a2[r]); a2[r] = fmaf(xv.w, A2.w, a2[r]);
                a3[r] = fmaf(xv.x, A3.x, a3[r]); a3[r] = fmaf(xv.y, A3.y, a3[r]);
                a3[r] = fmaf(xv.z, A3.z, a3[r]); a3[r] = fmaf(xv.w, A3.w, a3[r]);
            }
            const int kn = (k4 + 2) & 127;           // wrap at end (harmless reload)
            A0 = g0[(size_t)kn * 512];
            A1 = g1[(size_t)kn * 512];
            A2 = d0[(size_t)kn * 512];
            A3 = d1[(size_t)kn * 512];
#pragma unroll
            for (int r = 0; r < ROWS; ++r) {
                const float4 xv = *reinterpret_cast<const float4*>(&xs[r * DD + kk + 4]);
                a0[r] = fmaf(xv.x, B0.x, a0[r]); a0[r] = fmaf(xv.y, B0.y, a0[r]);
                a0[r] = fmaf(xv.z, B0.z, a0[r]); a0[r] = fmaf(xv.w, B0.w, a0[r]);
                a1[r] = fmaf(xv.x, B1.x, a1[r]); a1[r] = fmaf(xv.y, B1.y, a1[r]);
                a1[r] = fmaf(xv.z, B1.z, a1[r]); a1[r] = fmaf(xv.w, B1.w, a1[r]);
                a2[r] = fmaf(xv.x, B2.x, a2[r]); a2[r] = fmaf(xv.y, B2.y, a2[r]);
                a2[r] = fmaf(xv.z, B2.z, a2[r]); a2[r] = fmaf(xv.w, B2.w, a2[r]);
                a3[r] = fmaf(xv.x, B3.x, a3[r]); a3[r] = fmaf(xv.y, B3.y, a3[r]);
                a3[r] = fmaf(xv.z, B3.z, a3[r]); a3[r] = fmaf(xv.w, B3.w, a3[r]);
            }
        }

        // ================= LIF layer 1 (gc) -> bits1 + rowflag[0] ==============
#pragma unroll
        for (int r = 0; r < ROWS; ++r) {
            const float v0 = m1a[r] + ((a0[r] + bg0) - m1a[r]) * 0.5f;
            const bool s0 = (v0 - 1.0f) > 0.0f;
            m1a[r] = s0 ? 0.0f : v0;
            const unsigned long long k0 = __ballot(s0);
            const float v1 = m1b[r] + ((a1[r] + bg1) - m1b[r]) * 0.5f;
            const bool s1 = (v1 - 1.0f) > 0.0f;
            m1b[r] = s1 ? 0.0f : v1;
            const unsigned long long k1 = __ballot(s1);
            if (lane == 0) {
                bits1[r][wave] = k0; bits1[r][4 + wave] = k1;
                if (k0 | k1) atomicOr(&rowflag[0], 1u << r);
            }
        }
        __syncthreads();                                   // barrier A

        if (tid == 0) rowflag[2] = 0;                      // writer after barrier B

        // async-stage next t's x-tile; drains at barrier B
        if (t + 1 < TT) {
            const float* src = x + (((size_t)(t + 1) * B) + row0) * DD;
#pragma unroll
            for (int u = 0; u < 8; ++u)
                GLD_LDS(src + ((u * THREADS + tid) << 2), xs + ((u * THREADS + wave * 64) << 2));
        }

        // ================= layer 2 (pc): sparse bits1 -> bits2 + rowflag[1] ====
        {
            const unsigned int rf = rowflag[0];
#pragma unroll 1
            for (int r = 0; r < ROWS; ++r) {
                float p0 = bp0, p1 = bp1;
                if (rf & (1u << r)) {
#pragma unroll 1
                    for (int w = 0; w < 8; ++w) {
                        unsigned long long m = bits1[r][w];
                        while (m) {
                            const int b = __builtin_ctzll(m); m &= (m - 1);
                            const float* wp = Wpc + (size_t)((w << 6) + b) * HIDN + tid;
                            p0 += wp[0]; p1 += wp[256];
                        }
                    }
                }
                const float v0 = m2a[r] + (p0 - m2a[r]) * 0.5f;
                const bool s0 = (v0 - 1.0f) > 0.0f;
                m2a[r] = s0 ? 0.0f : v0;
                const unsigned long long k0 = __ballot(s0);
                const float v1 = m2b[r] + (p1 - m2b[r]) * 0.5f;
                const bool s1 = (v1 - 1.0f) > 0.0f;
                m2b[r] = s1 ? 0.0f : v1;
                const unsigned long long k1 = __ballot(s1);
                if (lane == 0) {
                    bits2[r][wave] = k0; bits2[r][4 + wave] = k1;
                    if (k0 | k1) atomicOr(&rowflag[1], 1u << r);
                }
            }
        }
        __syncthreads();                                   // barrier B

        if (tid == 0) rowflag[0] = 0;                      // writer after barrier C

        // ================= layer 3 (dcn): a2/a3 + sparse bits2 -> bits3 ========
        {
            const unsigned int rf = rowflag[1];
#pragma unroll 1
            for (int r = 0; r < ROWS; ++r) {
                float p0 = a2[r] + bd0, p1 = a3[r] + bd1;
                if (rf & (1u << r)) {
#pragma unroll 1
                    for (int w = 0; w < 8; ++w) {
                        unsigned long long m = bits2[r][w];
                        while (m) {
                            const int b = __builtin_ctzll(m); m &= (m - 1);
                            const float* wp = Wd1 + (size_t)(DD + (w << 6) + b) * HIDN + tid;
                            p0 += wp[0]; p1 += wp[256];
                        }
                    }
                }
                const float v0 = m3a[r] + (p0 - m3a[r]) * 0.5f;
                const bool s0 = (v0 - 1.0f) > 0.0f;
                m3a[r] = s0 ? 0.0f : v0;
                const unsigned long long k0 = __ballot(s0);
                const float v1 = m3b[r] + (p1 - m3b[r]) * 0.5f;
                const bool s1 = (v1 - 1.0f) > 0.0f;
                m3b[r] = s1 ? 0.0f : v1;
                const unsigned long long k1 = __ballot(s1);
                if (lane == 0) {
                    bits3[r][wave] = k0; bits3[r][4 + wave] = k1;
                    if (k0 | k1) atomicOr(&rowflag[2], 1u << r);
                }
            }
        }
        __syncthreads();                                   // barrier C

        if (tid == 0) rowflag[1] = 0;                      // writer after barrier A(t+1)

        // ================= output accumulation over s3 spikes ==================
        {
            const unsigned int rf = rowflag[2];
            if (owrite && (rf & (1u << orow))) {
#pragma unroll 1
                for (int w = 0; w < 8; ++w) {
                    unsigned long long m = bits3[orow][w];
                    while (m) {
                        const int b = __builtin_ctzll(m); m &= (m - 1);
                        out_acc += Wd2[(size_t)((w << 6) + b) * OUTN + ocol];
                    }
                }
            }
        }
    }

    if (owrite) {
        out[(row0 + orow) * OUTN + ocol] = out_acc * 0.0625f + bd2[ocol];
    }
}

extern "C" void kernel_launch(void* const* d_in, const int* in_sizes, int n_in,
                              void* d_out, int out_size, void* d_ws, size_t ws_size,
                              hipStream_t stream) {
    const float* x   = (const float*)d_in[0];
    const float* Wgc = (const float*)d_in[1];
    const float* bgc = (const float*)d_in[2];
    const float* Wpc = (const float*)d_in[3];
    const float* bpc = (const float*)d_in[4];
    const float* Wd1 = (const float*)d_in[5];
    const float* bd1 = (const float*)d_in[6];
    const float* Wd2 = (const float*)d_in[7];
    const float* bd2 = (const float*)d_in[8];
    const int B = in_sizes[0] / (TT * DD);

    float* pack = (float*)d_ws;   // 2 MB: [2][128][512][4]

    hipLaunchKernelGGL(pack_weights_kernel, dim3(2048), dim3(256), 0, stream,
                       Wgc, Wd1, pack);

    dim3 grid(B / ROWS), block(THREADS);
    hipLaunchKernelGGL(snn_fused_kernel, grid, block, 0, stream,
                       x, (const float4*)pack, bgc, Wpc, bpc, Wd1, bd1, Wd2, bd2,
                       (float*)d_out, B);
}